// Round 2
// baseline (637.350 us; speedup 1.0000x reference)
//
#include <hip/hip_runtime.h>

typedef float f32x4 __attribute__((ext_vector_type(4)));
typedef _Float16 f16x8 __attribute__((ext_vector_type(8)));
typedef _Float16 f16x4 __attribute__((ext_vector_type(4)));

#define M_TOT 16384
#define K_IN  4096
#define R_DIM 128
#define N_OUT 4096

__device__ __forceinline__ _Float16 sign_f16(float v) {
  return v > 0.f ? (_Float16)1.f : (v < 0.f ? (_Float16)-1.f : (_Float16)0.f);
}

// ---------- prep: VsT[r][k] = sign(V[k][r]) via LDS transpose; Us[n][r] = sign(U[n][r])
// grid 128 x 256. Block b transposes V k-slice [b*32, b*32+32) and signs one
// 4096-element chunk of U. LDS row stride 36 halfs (72 B) -> ~4-way write conflict, cheap.
__global__ __launch_bounds__(256)
void k_prep(const float* __restrict__ U, const float* __restrict__ V,
            _Float16* __restrict__ VsT, _Float16* __restrict__ Us) {
  __shared__ _Float16 tl[128 * 36];
  const int t = threadIdx.x;
  const int b = blockIdx.x;          // 0..127
  const int k0 = b * 32;

  // phase 1: coalesced V reads (consecutive t -> consecutive r)
#pragma unroll
  for (int e = 0; e < 16; ++e) {
    int idx = e * 256 + t;           // 0..4095
    int k = idx >> 7;                // 0..31
    int r = idx & 127;
    tl[r * 36 + k] = sign_f16(V[(size_t)(k0 + k) * R_DIM + r]);
  }
  __syncthreads();

  // phase 2: coalesced VsT row writes; thread -> (r = t>>1, 16-k half)
  {
    const int r = t >> 1;
    const int kh = (t & 1) * 16;
    f16x8 o0, o1;
#pragma unroll
    for (int j = 0; j < 8; ++j) {
      o0[j] = tl[r * 36 + kh + j];
      o1[j] = tl[r * 36 + kh + 8 + j];
    }
    *(f16x8*)(VsT + (size_t)r * K_IN + k0 + kh) = o0;
    *(f16x8*)(VsT + (size_t)r * K_IN + k0 + kh + 8) = o1;
  }

  // Us: elementwise sign, fully coalesced f32x4 reads / f16x4 writes
#pragma unroll
  for (int e = 0; e < 4; ++e) {
    size_t base = (size_t)b * 4096 + (size_t)e * 1024 + (size_t)t * 4;
    f32x4 u = *(const f32x4*)(U + base);
    f16x4 s;
#pragma unroll
    for (int j = 0; j < 4; ++j) s[j] = sign_f16(u[j]);
    *(f16x4*)(Us + base) = s;
  }
}

// ---------- kernel 1: Z2[half][m][r] = sum_{k in half} x[m][k]*s2[k]*sign(V[k][r])
// LDS-free, barrier-free. Each wave: 16 rows x 128 cols, K split in 2 halves of 2048.
// 2048 waves total: grid 512 x 256 (4 waves/block), 2 waves/SIMD.
// A: direct coalesced x loads -> f16 hi/lo split in regs. B: direct loads from
// L2-resident VsT (1 MB). acc 8 x f32x4 = 32 VGPR; bfr 32; total ~105 VGPR.
__global__ __launch_bounds__(256, 2)
void k1_z(const float* __restrict__ x, const float* __restrict__ s2,
          const _Float16* __restrict__ VsT, float* __restrict__ Z2) {
  const int t = threadIdx.x;
  const int lane = t & 63;
  const int wave = t >> 6;
  const int wid = blockIdx.x * 4 + wave;
  const int half = wid & 1;
  const int g = wid >> 1;            // 0..1023
  const int m0 = g * 16;
  const int k0 = half * 2048;
  const int row = lane & 15;         // A row / B col within 16-group
  const int kq = (lane >> 4) * 8;    // this lane's 8-k sub-chunk

  const float* xp = x + (size_t)(m0 + row) * K_IN + k0 + kq;
  const float* sp = s2 + k0 + kq;
  const _Float16* bp = VsT + (size_t)row * K_IN + k0 + kq;

  f32x4 acc[8];
#pragma unroll
  for (int i = 0; i < 8; ++i) acc[i] = (f32x4){0.f, 0.f, 0.f, 0.f};

  // prefetch step 0
  f32x4 xa0 = *(const f32x4*)xp;
  f32x4 xa1 = *(const f32x4*)(xp + 4);
  f32x4 sa0 = *(const f32x4*)sp;
  f32x4 sa1 = *(const f32x4*)(sp + 4);

  for (int st = 0; st < 64; ++st) {
    // B fragments for this 32-k step (8 col-groups cover R=128)
    f16x8 bfr[8];
#pragma unroll
    for (int nf = 0; nf < 8; ++nf)
      bfr[nf] = *(const f16x8*)(bp + (size_t)nf * 16 * K_IN + st * 32);

    // convert A: f16 hi/lo pair (exact to ~2^-23 rel)
    f16x8 ah, al;
#pragma unroll
    for (int j = 0; j < 4; ++j) {
      float f0 = xa0[j] * sa0[j];
      float f1 = xa1[j] * sa1[j];
      _Float16 h0 = (_Float16)f0;
      _Float16 h1 = (_Float16)f1;
      ah[j] = h0;
      ah[j + 4] = h1;
      al[j] = (_Float16)(f0 - (float)h0);
      al[j + 4] = (_Float16)(f1 - (float)h1);
    }

    // prefetch next step's A (wraps at end; redundant load harmless)
    const int sn = (st + 1) & 63;
    xa0 = *(const f32x4*)(xp + sn * 32);
    xa1 = *(const f32x4*)(xp + sn * 32 + 4);
    sa0 = *(const f32x4*)(sp + sn * 32);
    sa1 = *(const f32x4*)(sp + sn * 32 + 4);

#pragma unroll
    for (int nf = 0; nf < 8; ++nf) {
      acc[nf] = __builtin_amdgcn_mfma_f32_16x16x32_f16(ah, bfr[nf], acc[nf], 0, 0, 0);
      acc[nf] = __builtin_amdgcn_mfma_f32_16x16x32_f16(al, bfr[nf], acc[nf], 0, 0, 0);
    }
  }

  // epilogue: C layout col = lane&15, row = (lane>>4)*4 + j
  float* Zp = Z2 + (size_t)half * M_TOT * R_DIM;
  const int rw = m0 + (lane >> 4) * 4;
#pragma unroll
  for (int nf = 0; nf < 8; ++nf) {
    const int col = nf * 16 + row;
#pragma unroll
    for (int j = 0; j < 4; ++j)
      Zp[(size_t)(rw + j) * R_DIM + col] = acc[nf][j];
  }
}

// ---------- kernel 2: out[m][n] = (sum_r (Za+Zb)[m][r] * sign(U[n][r]))*s1[n]+bias[n]
// BM=128, BN=128, 512 threads (8 waves as 2x4), grid 4096 (nb-fast: 32 blocks share Z tile).
// acc 8 x f32x4 = 32 VGPR, bf 8 frags = 32 VGPR -> no spill at (512,4).
__global__ __launch_bounds__(512, 4)
void k2_out(const float* __restrict__ Z2, const _Float16* __restrict__ Us,
            const float* __restrict__ s1, const float* __restrict__ bias,
            float* __restrict__ out) {
  __shared__ _Float16 Zhi[128 * 128];   // 32 KB, row = 256 B, XOR-swizzled
  __shared__ _Float16 Zlo[128 * 128];   // 32 KB

  const int t = threadIdx.x;
  const int lane = t & 63;
  const int wave = t >> 6;
  const int bid = blockIdx.x;
  const int nb = bid & 31;
  const int mb = bid >> 5;
  const int m0 = mb * 128, n0 = nb * 128;
  const int wm = wave & 1, wn = wave >> 1;  // 64-row half x 32-col quarter

  // B fragments in registers: 4 ks x 2 nf
  f16x8 bf[4][2];
#pragma unroll
  for (int ks = 0; ks < 4; ++ks)
#pragma unroll
    for (int nf = 0; nf < 2; ++nf) {
      const int n = n0 + wn * 32 + nf * 16 + (lane & 15);
      bf[ks][nf] = *(const f16x8*)(Us + (size_t)n * R_DIM + ks * 32 + (lane >> 4) * 8);
    }

  // stage: Zsum = Za + Zb -> f16 hi/lo LDS (swizzled)
  {
    const int sr = t >> 2;             // 0..127
    const int skf = (t & 3) * 32;
    const float* za = Z2 + (size_t)(m0 + sr) * R_DIM + skf;
    const float* zb = za + (size_t)M_TOT * R_DIM;
    const int swr = (sr & 7) << 4;
#pragma unroll
    for (int q = 0; q < 4; ++q) {
      f32x4 a0 = *(const f32x4*)(za + q * 8);
      f32x4 a1 = *(const f32x4*)(za + q * 8 + 4);
      f32x4 b0 = *(const f32x4*)(zb + q * 8);
      f32x4 b1 = *(const f32x4*)(zb + q * 8 + 4);
      f16x8 h, l;
#pragma unroll
      for (int j = 0; j < 4; ++j) {
        float f0 = a0[j] + b0[j];
        float f1 = a1[j] + b1[j];
        _Float16 h0 = (_Float16)f0, h1 = (_Float16)f1;
        h[j] = h0;
        h[j + 4] = h1;
        l[j] = (_Float16)(f0 - (float)h0);
        l[j + 4] = (_Float16)(f1 - (float)h1);
      }
      const int off = sr * 256 + ((((t & 3) * 64) + q * 16) ^ swr);
      *(f16x8*)((char*)Zhi + off) = h;
      *(f16x8*)((char*)Zlo + off) = l;
    }
  }
  __syncthreads();

  f32x4 acc[4][2] = {};
  const int rsw = (lane & 7) << 4;
  const int kg = (lane >> 4) * 16;
#pragma unroll
  for (int mf = 0; mf < 4; ++mf) {
    const int r = wm * 64 + mf * 16 + (lane & 15);
    const int rbase = r * 256;
#pragma unroll
    for (int ks = 0; ks < 4; ++ks) {
      const int kb = ks * 64 + kg;
      f16x8 ah = *(const f16x8*)((const char*)Zhi + rbase + (kb ^ rsw));
      f16x8 al = *(const f16x8*)((const char*)Zlo + rbase + (kb ^ rsw));
#pragma unroll
      for (int nf = 0; nf < 2; ++nf) {
        acc[mf][nf] = __builtin_amdgcn_mfma_f32_16x16x32_f16(ah, bf[ks][nf], acc[mf][nf], 0, 0, 0);
        acc[mf][nf] = __builtin_amdgcn_mfma_f32_16x16x32_f16(al, bf[ks][nf], acc[mf][nf], 0, 0, 0);
      }
    }
  }

  // epilogue: scale + bias
#pragma unroll
  for (int nf = 0; nf < 2; ++nf) {
    const int col = n0 + wn * 32 + nf * 16 + (lane & 15);
    const float sv = s1[col];
    const float bv = bias[col];
#pragma unroll
    for (int mf = 0; mf < 4; ++mf) {
      const int row2 = m0 + wm * 64 + mf * 16 + (lane >> 4) * 4;
#pragma unroll
      for (int j = 0; j < 4; ++j)
        out[(size_t)(row2 + j) * N_OUT + col] = acc[mf][nf][j] * sv + bv;
    }
  }
}

extern "C" void kernel_launch(void* const* d_in, const int* in_sizes, int n_in,
                              void* d_out, int out_size, void* d_ws, size_t ws_size,
                              hipStream_t stream) {
  const float* x    = (const float*)d_in[0];
  const float* U    = (const float*)d_in[1];
  const float* V    = (const float*)d_in[2];
  const float* s1   = (const float*)d_in[3];
  const float* s2   = (const float*)d_in[4];
  const float* bias = (const float*)d_in[5];
  float* out = (float*)d_out;

  // ws layout: VsT (1 MB f16) | Us (1 MB f16) | Z2 (2 x 16384 x 128 f32 = 16 MB)
  _Float16* VsT = (_Float16*)d_ws;
  _Float16* Us  = VsT + (size_t)R_DIM * K_IN;
  float*    Z2  = (float*)(Us + (size_t)N_OUT * R_DIM);

  k_prep<<<dim3(128), dim3(256), 0, stream>>>(U, V, VsT, Us);
  k1_z<<<dim3(512), dim3(256), 0, stream>>>(x, s2, VsT, Z2);
  k2_out<<<dim3(4096), dim3(512), 0, stream>>>(Z2, Us, s1, bias, out);
}

// Round 9
// 524.523 us; speedup vs baseline: 1.2151x; 1.2151x over previous
//
#include <hip/hip_runtime.h>

typedef float f32x4 __attribute__((ext_vector_type(4)));
typedef _Float16 f16x8 __attribute__((ext_vector_type(8)));
typedef __fp16 fp16x2 __attribute__((ext_vector_type(2)));   // cvt_pkrtz return type

#define M_TOT 16384
#define K_IN  4096
#define R_DIM 128
#define N_OUT 4096

__device__ __forceinline__ _Float16 sign_f16(float v) {
  return v > 0.f ? (_Float16)1.f : (v < 0.f ? (_Float16)-1.f : (_Float16)0.f);
}

// f32x4 pair -> f16 hi + f16 lo (pair sum accurate to ~2^-21 rel)
__device__ __forceinline__ void cvt8v(f32x4 a, f32x4 b, f16x8& h, f16x8& l) {
#pragma unroll
  for (int j = 0; j < 2; ++j) {
    fp16x2 h0 = __builtin_amdgcn_cvt_pkrtz(a[2 * j], a[2 * j + 1]);
    fp16x2 h1 = __builtin_amdgcn_cvt_pkrtz(b[2 * j], b[2 * j + 1]);
    fp16x2 l0 = __builtin_amdgcn_cvt_pkrtz(a[2 * j] - (float)h0[0], a[2 * j + 1] - (float)h0[1]);
    fp16x2 l1 = __builtin_amdgcn_cvt_pkrtz(b[2 * j] - (float)h1[0], b[2 * j + 1] - (float)h1[1]);
    h[2 * j] = (_Float16)h0[0]; h[2 * j + 1] = (_Float16)h0[1];
    h[4 + 2 * j] = (_Float16)h1[0]; h[5 + 2 * j] = (_Float16)h1[1];
    l[2 * j] = (_Float16)l0[0]; l[2 * j + 1] = (_Float16)l0[1];
    l[4 + 2 * j] = (_Float16)l1[0]; l[5 + 2 * j] = (_Float16)l1[1];
  }
}

__device__ __forceinline__ void gload16(const void* g, void* l) {
  __builtin_amdgcn_global_load_lds((const __attribute__((address_space(1))) unsigned int*)g,
                                   (__attribute__((address_space(3))) unsigned int*)l, 16, 0, 0);
}

// ---------------- prep ----------------------------------------------------
// VsT_sw: 64 tiles (one per K-step of 64) of [r=128][64 k] f16, byte-swizzled
//   within tile: byte(r, cB) = r*128 + (cB ^ ((r&7)<<4)); value sign(V[kt*64+cB/2][r]).
// Us: plain [n][r] f16 sign(U[n][r]).
__global__ __launch_bounds__(256)
void k_prep(const float* __restrict__ U, const float* __restrict__ V,
            _Float16* __restrict__ VsT_sw, _Float16* __restrict__ Us) {
  __shared__ _Float16 tl[128 * 72];
  const int t = threadIdx.x;
  const int b = blockIdx.x;          // 0..255

  // Us chunk (all blocks): 2048 halfs each
  {
    size_t base = (size_t)b * 2048 + (size_t)t * 8;
    f32x4 u0 = *(const f32x4*)(U + base);
    f32x4 u1 = *(const f32x4*)(U + base + 4);
    f16x8 s;
#pragma unroll
    for (int j = 0; j < 4; ++j) { s[j] = sign_f16(u0[j]); s[j + 4] = sign_f16(u1[j]); }
    *(f16x8*)(Us + base) = s;
  }

  if (b < 64) {                      // V tile: k in [64b, 64b+64)
    // phase 1: coalesced V reads -> transposed sign in LDS
#pragma unroll
    for (int it = 0; it < 8; ++it) {
      int idx4 = it * 256 + t;       // 0..2047
      int kl = idx4 >> 5;            // 0..63
      int r4 = (idx4 & 31) * 4;
      f32x4 v = *(const f32x4*)(V + (size_t)(b * 64 + kl) * R_DIM + r4);
#pragma unroll
      for (int j = 0; j < 4; ++j) tl[(r4 + j) * 72 + kl] = sign_f16(v[j]);
    }
    __syncthreads();
    // phase 2: write swizzled tile, coalesced 16B chunks
#pragma unroll
    for (int c = 0; c < 4; ++c) {
      int off = t * 64 + c * 16;     // byte offset in 16KB tile
      int r = off >> 7;
      int cB = (off & 127) ^ ((r & 7) << 4);
      f16x8 o = *(const f16x8*)(tl + r * 72 + (cB >> 1));
      *(f16x8*)((char*)VsT_sw + (size_t)b * 16384 + off) = o;
    }
  }
}

// ---------------- kernel 1: Z[m][r] = sum_k x[m][k]*s2[k]*sign(V[k][r]) ----
// BM=32, BN=128(=R), BK=64, 256 thr (4 waves as 2x2), grid 512, dbuf LDS 48KB.
// Output written as pre-swizzled f16 hi/lo: byte(m,cB) = m*256 + (cB ^ ((m&7)<<4)).
__global__ __launch_bounds__(256, 3)
void k1_z(const float* __restrict__ x, const float* __restrict__ s2,
          const _Float16* __restrict__ VsT_sw,
          _Float16* __restrict__ Zswh, _Float16* __restrict__ Zswl) {
  __shared__ char smem[49152];       // Ah0@0 Al0@4K Ah1@8K Al1@12K B0@16K B1@32K
  const int t = threadIdx.x;
  const int lane = t & 63;
  const int wave = t >> 6;
  const int m0 = blockIdx.x * 32;

  // A staging map: thread -> (row, 8 f32)
  const int srow = t >> 3;                 // 0..31
  const int scol = (t & 7) * 8;            // f32 col in 64-wide tile
  const float* xrow = x + (size_t)(m0 + srow) * K_IN + scol;
  const int aoff = srow * 128 + (((t & 7) * 16) ^ ((srow & 7) << 4));

  // fragment maps
  const int wr = wave & 1, wc = wave >> 1;
  const int arow = wr * 16 + (lane & 15);
  const int abyte = arow * 128;
  const int asw = (arow & 7) << 4;
  const int kq16 = (lane >> 4) * 16;       // byte offset of lane's 8-k group
  int brow[4], bsw[4];
#pragma unroll
  for (int nf = 0; nf < 4; ++nf) {
    brow[nf] = wc * 64 + nf * 16 + (lane & 15);
    bsw[nf] = (brow[nf] & 7) << 4;
  }

  f32x4 acc[4];
#pragma unroll
  for (int i = 0; i < 4; ++i) acc[i] = (f32x4){0.f, 0.f, 0.f, 0.f};

  // ---- prologue: stage tile 0
  {
    f32x4 a = *(const f32x4*)xrow;
    f32x4 bql = *(const f32x4*)(xrow + 4);
    f32x4 sa = *(const f32x4*)(s2 + scol);
    f32x4 sb = *(const f32x4*)(s2 + scol + 4);
    f16x8 h, l;
    cvt8v(a * sa, bql * sb, h, l);
    *(f16x8*)(smem + aoff) = h;
    *(f16x8*)(smem + 4096 + aoff) = l;
#pragma unroll
    for (int q = 0; q < 4; ++q)
      gload16((const char*)VsT_sw + (size_t)wave * 1024 + q * 4096 + lane * 16,
              smem + 16384 + wave * 1024 + q * 4096);
  }
  __syncthreads();

  // prefetch x for tile 1
  f32x4 xn0 = *(const f32x4*)(xrow + 64);
  f32x4 xn1 = *(const f32x4*)(xrow + 68);
  f32x4 sn0 = *(const f32x4*)(s2 + 64 + scol);
  f32x4 sn1 = *(const f32x4*)(s2 + 64 + scol + 4);

  for (int kt = 0; kt < 64; ++kt) {
    const int cur = kt & 1, nxt = cur ^ 1;
    if (kt < 63) {
      // stage next B via async gload (linear dest; source pre-swizzled)
#pragma unroll
      for (int q = 0; q < 4; ++q)
        gload16((const char*)VsT_sw + (size_t)(kt + 1) * 16384 + wave * 1024 + q * 4096 + lane * 16,
                smem + 16384 + nxt * 16384 + wave * 1024 + q * 4096);
      // convert prefetched x -> A hi/lo (compiler auto-waits on xn)
      f16x8 h, l;
      cvt8v(xn0 * sn0, xn1 * sn1, h, l);
      *(f16x8*)(smem + nxt * 8192 + aoff) = h;
      *(f16x8*)(smem + nxt * 8192 + 4096 + aoff) = l;
      if (kt < 62) {
        xn0 = *(const f32x4*)(xrow + (kt + 2) * 64);
        xn1 = *(const f32x4*)(xrow + (kt + 2) * 64 + 4);
        sn0 = *(const f32x4*)(s2 + (kt + 2) * 64 + scol);
        sn1 = *(const f32x4*)(s2 + (kt + 2) * 64 + scol + 4);
      }
    }
    // compute current tile
#pragma unroll
    for (int kk = 0; kk < 2; ++kk) {
      const int cb = kk * 64 + kq16;
      f16x8 ah = *(const f16x8*)(smem + cur * 8192 + abyte + (cb ^ asw));
      f16x8 al = *(const f16x8*)(smem + cur * 8192 + 4096 + abyte + (cb ^ asw));
#pragma unroll
      for (int nf = 0; nf < 4; ++nf) {
        f16x8 bfv = *(const f16x8*)(smem + 16384 + cur * 16384 + brow[nf] * 128 + (cb ^ bsw[nf]));
        acc[nf] = __builtin_amdgcn_mfma_f32_16x16x32_f16(ah, bfv, acc[nf], 0, 0, 0);
        acc[nf] = __builtin_amdgcn_mfma_f32_16x16x32_f16(al, bfv, acc[nf], 0, 0, 0);
      }
    }
    __syncthreads();
  }

  // ---- epilogue: shuffle via LDS, convert once, write pre-swizzled Z
  float* ZT = (float*)smem;                 // 32 x 132 f32 = 16.9 KB
#pragma unroll
  for (int nf = 0; nf < 4; ++nf)
#pragma unroll
    for (int j = 0; j < 4; ++j)
      ZT[(wr * 16 + (lane >> 4) * 4 + j) * 132 + wc * 64 + nf * 16 + (lane & 15)] = acc[nf][j];
  __syncthreads();
  {
    const int lr = t >> 3;
    const int c0 = (t & 7) * 16;            // f32 col base
    f32x4 v0 = *(const f32x4*)(ZT + lr * 132 + c0);
    f32x4 v1 = *(const f32x4*)(ZT + lr * 132 + c0 + 4);
    f32x4 v2 = *(const f32x4*)(ZT + lr * 132 + c0 + 8);
    f32x4 v3 = *(const f32x4*)(ZT + lr * 132 + c0 + 12);
    f16x8 h0, l0, h1, l1;
    cvt8v(v0, v1, h0, l0);
    cvt8v(v2, v3, h1, l1);
    const int m = m0 + lr;
    const int sw = (lr & 7) << 4;
    char* ph = (char*)Zswh + (size_t)m * 256;
    char* pl = (char*)Zswl + (size_t)m * 256;
    *(f16x8*)(ph + ((c0 * 2) ^ sw)) = h0;
    *(f16x8*)(ph + ((c0 * 2 + 16) ^ sw)) = h1;
    *(f16x8*)(pl + ((c0 * 2) ^ sw)) = l0;
    *(f16x8*)(pl + ((c0 * 2 + 16) ^ sw)) = l1;
  }
}

// ---------------- kernel 2: out = (Z @ signU^T)*s1 + bias -----------------
// BM=64, BN=128, 256 thr (4 waves as 2x2), grid 8192 (nb-fast), LDS 32KB.
// Z staged via pure gload_lds (already f16 hi/lo, pre-swizzled). bf held in regs.
__global__ __launch_bounds__(256, 4)
void k2_out(const _Float16* __restrict__ Zswh, const _Float16* __restrict__ Zswl,
            const _Float16* __restrict__ Us, const float* __restrict__ s1,
            const float* __restrict__ bias, float* __restrict__ out) {
  __shared__ char smem[32768];              // Zh 16K @0, Zl 16K @16K
  const int t = threadIdx.x;
  const int lane = t & 63;
  const int wave = t >> 6;
  const int bid = blockIdx.x;
  const int nb = bid & 31;                  // nb-fast: 32 blocks share a Z chunk
  const int mb = bid >> 5;
  const int m0 = mb * 64, n0 = nb * 128;
  const int wm = wave & 1, wn = wave >> 1;  // 32-row half x 64-col half

  // B fragments held in registers
  f16x8 bf[4][4];
#pragma unroll
  for (int ks = 0; ks < 4; ++ks)
#pragma unroll
    for (int nf = 0; nf < 4; ++nf) {
      const int n = n0 + wn * 64 + nf * 16 + (lane & 15);
      bf[ks][nf] = *(const f16x8*)(Us + (size_t)n * R_DIM + ks * 32 + (lane >> 4) * 8);
    }

  // stage Z rows [m0, m0+64) : 16KB per array, linear copy
  const char* gh = (const char*)Zswh + (size_t)m0 * 256;
  const char* gl = (const char*)Zswl + (size_t)m0 * 256;
#pragma unroll
  for (int q = 0; q < 4; ++q) {
    gload16(gh + wave * 1024 + q * 4096 + lane * 16, smem + wave * 1024 + q * 4096);
    gload16(gl + wave * 1024 + q * 4096 + lane * 16, smem + 16384 + wave * 1024 + q * 4096);
  }
  __syncthreads();

  f32x4 acc[2][4] = {};
  const int kq = (lane >> 4) * 16;          // byte
#pragma unroll
  for (int mf = 0; mf < 2; ++mf) {
    const int lr = wm * 32 + mf * 16 + (lane & 15);
    const int sw = (lr & 7) << 4;
#pragma unroll
    for (int ks = 0; ks < 4; ++ks) {
      const int cb = (ks * 64 + kq) ^ sw;
      f16x8 ah = *(const f16x8*)(smem + lr * 256 + cb);
      f16x8 al = *(const f16x8*)(smem + 16384 + lr * 256 + cb);
#pragma unroll
      for (int nf = 0; nf < 4; ++nf) {
        acc[mf][nf] = __builtin_amdgcn_mfma_f32_16x16x32_f16(ah, bf[ks][nf], acc[mf][nf], 0, 0, 0);
        acc[mf][nf] = __builtin_amdgcn_mfma_f32_16x16x32_f16(al, bf[ks][nf], acc[mf][nf], 0, 0, 0);
      }
    }
  }

  // epilogue: scale + bias
#pragma unroll
  for (int nf = 0; nf < 4; ++nf) {
    const int col = n0 + wn * 64 + nf * 16 + (lane & 15);
    const float sv = s1[col];
    const float bv = bias[col];
#pragma unroll
    for (int mf = 0; mf < 2; ++mf) {
      const int row = m0 + wm * 32 + mf * 16 + (lane >> 4) * 4;
#pragma unroll
      for (int j = 0; j < 4; ++j)
        out[(size_t)(row + j) * N_OUT + col] = acc[mf][nf][j] * sv + bv;
    }
  }
}

extern "C" void kernel_launch(void* const* d_in, const int* in_sizes, int n_in,
                              void* d_out, int out_size, void* d_ws, size_t ws_size,
                              hipStream_t stream) {
  const float* x    = (const float*)d_in[0];
  const float* U    = (const float*)d_in[1];
  const float* V    = (const float*)d_in[2];
  const float* s1   = (const float*)d_in[3];
  const float* s2   = (const float*)d_in[4];
  const float* bias = (const float*)d_in[5];
  float* out = (float*)d_out;

  // ws: VsT_sw 1MB | Us 1MB | Zswh 4MB | Zswl 4MB
  char* w = (char*)d_ws;
  _Float16* VsT_sw = (_Float16*)(w);
  _Float16* Us     = (_Float16*)(w + (1 << 20));
  _Float16* Zswh   = (_Float16*)(w + (2 << 20));
  _Float16* Zswl   = (_Float16*)(w + (6 << 20));

  k_prep<<<dim3(256), dim3(256), 0, stream>>>(U, V, VsT_sw, Us);
  k1_z<<<dim3(512), dim3(256), 0, stream>>>(x, s2, VsT_sw, Zswh, Zswl);
  k2_out<<<dim3(8192), dim3(256), 0, stream>>>(Zswh, Zswl, Us, s1, bias, out);
}